// Round 1
// baseline (743.624 us; speedup 1.0000x reference)
//
#include <hip/hip_runtime.h>
#include <math.h>

#define BB 64
#define DD 512
#define MM 8192
#define TPB 1024
#define CPT 8   // MM / TPB columns per thread in the scan

// ---------------- K0: G = K K^T  (G[t][s] = k_t . k_s; diag = ||k_t||^2) ----------------
__global__ __launch_bounds__(1024) void k0_gram(const float* __restrict__ K, float* __restrict__ G) {
    __shared__ float Ks[BB][129];          // +1 pad breaks the stride-128 bank collision
    int tid = threadIdx.x;
    int s = tid & 63, tq = tid >> 6;       // tq in 0..15
    float acc[4] = {0.f, 0.f, 0.f, 0.f};
    for (int d0 = 0; d0 < DD; d0 += 128) {
        #pragma unroll
        for (int i = 0; i < 8; ++i) {
            int e = i * 1024 + tid; int r = e >> 7, c = e & 127;
            Ks[r][c] = K[r * DD + d0 + c];
        }
        __syncthreads();
        for (int dl = 0; dl < 128; ++dl) {
            float kv = Ks[s][dl];          // lane-distinct rows, padded: conflict-free
            #pragma unroll
            for (int i = 0; i < 4; ++i) acc[i] += Ks[tq * 4 + i][dl] * kv;  // wave-uniform: broadcast
        }
        __syncthreads();
    }
    #pragma unroll
    for (int i = 0; i < 4; ++i) G[(tq * 4 + i) * BB + s] = acc[i];
}

// ---------------- K1: S0 = K @ MK0  [B,M]  and n2init[j] = ||MK0[:,j]||^2 ----------------
__global__ __launch_bounds__(256) void k1_s0(const float* __restrict__ K, const float* __restrict__ MK0,
                                             float* __restrict__ S0, float* __restrict__ n2) {
    __shared__ float Ks[64][64];
    __shared__ float Ms[64][64];
    __shared__ float sq[4][64];
    int tid = threadIdx.x;
    int jb = blockIdx.x * 64;              // 128 blocks cover M
    int jl = tid & 63, tq = tid >> 6;
    float acc[16];
    #pragma unroll
    for (int i = 0; i < 16; ++i) acc[i] = 0.f;
    float sqa = 0.f;
    for (int d0 = 0; d0 < DD; d0 += 64) {
        #pragma unroll
        for (int i = 0; i < 16; ++i) {
            int e = i * 256 + tid; int r = e >> 6, c = e & 63;   // c == jl always
            Ks[r][c] = K[r * DD + d0 + c];
            float m = MK0[(d0 + r) * MM + jb + c];
            Ms[r][c] = m;
            sqa += m * m;                   // per-thread partial sumsq of column jl
        }
        __syncthreads();
        for (int dl = 0; dl < 64; ++dl) {
            float mv = Ms[dl][jl];          // 2-way aliasing: free
            #pragma unroll
            for (int i = 0; i < 16; ++i) acc[i] += Ks[tq * 16 + i][dl] * mv;  // broadcast
        }
        __syncthreads();
    }
    #pragma unroll
    for (int i = 0; i < 16; ++i) S0[(tq * 16 + i) * MM + jb + jl] = acc[i];
    sq[tq][jl] = sqa;
    __syncthreads();
    if (tq == 0) n2[jb + jl] = sq[0][jl] + sq[1][jl] + sq[2][jl] + sq[3][jl];
}

// ---------------- K2: the 64-step scan (single block, per-column state in registers) ----------------
__global__ __launch_bounds__(1024) void k2_scan(const float* __restrict__ S0,
                                                const float* __restrict__ G,
                                                const float* __restrict__ n2init,
                                                const float* __restrict__ bp,
                                                const float* __restrict__ gp,
                                                float* __restrict__ Wra,   // [B][M]: w_r * alive(post-zero)
                                                float* __restrict__ A) {   // [B][B]: a_t[s]
    __shared__ float Grow[BB];
    __shared__ float Pfx[BB];              // P_t[s] = sum_{s'=s}^{t-1} G[t,s']
    __shared__ float E[BB];                // e_t at hot column of history slot s
    __shared__ int   lastocc[BB];          // slot s is the LAST zeroing of its column (<= t)
    __shared__ float red_f[16];
    __shared__ unsigned long long red_u[16];

    const int tid = threadIdx.x;
    const int lane = tid & 63;
    const int wid = tid >> 6;

    const float beta  = 1.f / (1.f + expf(-bp[0]));
    const float gamma = gp[0];
    const float cuni  = beta / (float)MM;  // uniform write coefficient c = beta*mean(w_r), mean = 1/M
    const float omb   = 1.f - beta;

    float n2v[CPT], wu[CPT], alive[CPT];
    int lz[CPT];
    unsigned long long mask[CPT];          // history-slot bits owned by this column
    #pragma unroll
    for (int c = 0; c < CPT; ++c) {
        n2v[c] = n2init[c * TPB + tid];
        wu[c] = 0.f; alive[c] = 1.f; lz[c] = 0; mask[c] = 0ull;
    }
    if (tid < BB) lastocc[tid] = 0;
    int j0 = 0;          // argmin of all-zero w_u at t=0 is index 0 (first-index tie-break)
    int j0prev = -1;
    __syncthreads();

    for (int t = 0; t < BB; ++t) {
        // stage G row t
        if (tid < BB) Grow[tid] = G[t * BB + tid];
        __syncthreads();
        // suffix sums of G row (wave 0)
        if (tid < BB) {
            float x = (tid < t) ? Grow[tid] : 0.f;
            #pragma unroll
            for (int o = 1; o < 64; o <<= 1) {
                float y = __shfl_down(x, o);
                if (tid + o < 64) x += y;
            }
            Pfx[tid] = x;
        }
        __syncthreads();
        const float k2t = Grow[t];
        const float invk = 1.f / sqrtf(k2t);

        // ---- phase A: per-column dot/cos/e; hot-column bookkeeping ----
        float e[CPT], dot[CPT];
        float psum = 0.f;
        #pragma unroll
        for (int c = 0; c < CPT; ++c) {
            int j = c * TPB + tid;
            float d_ = alive[c] * S0[t * MM + j] + cuni * Pfx[lz[c]];
            if (lz[c] >= 1) d_ += omb * Grow[lz[c]];          // surviving one-hot write
            float cosv = d_ * invk / sqrtf(n2v[c]);
            float ee = expf(cosv);                            // cos in [-1,1]: no max-subtract needed
            e[c] = ee; dot[c] = d_;
            psum += ee;
            if (j == j0) {                                    // this step's zeroed column
                unsigned long long mm = mask[c];
                while (mm) { int sb = __builtin_ctzll(mm); lastocc[sb] = 0; mm &= mm - 1; }
                mask[c] |= (1ull << t);
                lastocc[t] = 1;
            }
        }
        // refresh E at owned history slots with current e
        #pragma unroll
        for (int c = 0; c < CPT; ++c) {
            unsigned long long mm = mask[c];
            while (mm) { int sb = __builtin_ctzll(mm); E[sb] = e[c]; mm &= mm - 1; }
        }
        // reduce S = sum(e)
        float v = psum;
        #pragma unroll
        for (int o = 32; o > 0; o >>= 1) v += __shfl_down(v, o);
        if (lane == 0) red_f[wid] = v;
        __syncthreads();
        float S = 0.f;
        #pragma unroll
        for (int w = 0; w < 16; ++w) S += red_f[w];
        const float invS = 1.f / S;

        // ---- A row t (wave 0): a_t[s] = (c*Qe[s] + (1-b)*lastocc[s]*E[s]) / S ----
        if (tid < BB) {
            int s = tid;
            float ev = (s <= t && lastocc[s]) ? E[s] : 0.f;
            float x = ev;
            #pragma unroll
            for (int o = 1; o < 64; o <<= 1) {
                float y = __shfl_down(x, o);
                if (s + o < 64) x += y;
            }
            float suf = x - ev;            // sum over slots s' in (s, t] with lastocc
            float arow = 0.f;
            if (s < t) {
                float Qe = S - suf;
                arow = cuni * Qe;
                if (s >= 1 && lastocc[s]) arow += omb * E[s];
                arow *= invS;
            }
            A[t * BB + s] = arow;
        }

        // ---- phase B: w_u update, Wra, n2, argmin ----
        unsigned long long mymin = 0xFFFFFFFFFFFFFFFFull;
        #pragma unroll
        for (int c = 0; c < CPT; ++c) {
            int j = c * TPB + tid;
            float wr = e[c] * invS;
            // carry w_w = beta*mean + (1-beta)*onehot(j0_{t-1}) (zero at t=0; no one-hot at t=1)
            float wwold = (t == 0) ? 0.f : (cuni + ((t >= 2 && j == j0prev) ? omb : 0.f));
            float wun = gamma * wu[c] + wr + wwold;
            wu[c] = wun;
            bool isj0 = (j == j0);
            float ap = isj0 ? 0.f : alive[c];
            Wra[t * MM + j] = wr * ap;
            alive[c] = ap;
            float wwnew = cuni + ((t >= 1 && isj0) ? omb : 0.f);
            float dz = isj0 ? 0.f : dot[c];
            float nz = isj0 ? 0.f : n2v[c];
            n2v[c] = nz + 2.f * wwnew * dz + wwnew * wwnew * k2t;   // ||col + w*k||^2
            if (isj0) lz[c] = t;
            // argmin with first-index tie-break (w_u >= 0 so raw bits are order-preserving)
            unsigned long long key = ((unsigned long long)__float_as_uint(wun) << 32) | (unsigned)j;
            mymin = (key < mymin) ? key : mymin;
        }
        unsigned long long mv = mymin;
        #pragma unroll
        for (int o = 32; o > 0; o >>= 1) {
            unsigned long long ov = __shfl_down(mv, o);
            mv = (ov < mv) ? ov : mv;
        }
        if (lane == 0) red_u[wid] = mv;
        __syncthreads();
        unsigned long long best = 0xFFFFFFFFFFFFFFFFull;
        #pragma unroll
        for (int w = 0; w < 16; ++w) { unsigned long long q = red_u[w]; best = (q < best) ? q : best; }
        j0prev = j0;
        j0 = (int)(best & 0xFFFFFFFFu);    // next step's zeroed column = this argmin
    }
}

// ---------------- K3: parts[jslice][t][d] = sum_{j in slice} Wra[t,j] * MK0[d,j] ----------------
__global__ __launch_bounds__(256) void k3_u1(const float* __restrict__ Wra, const float* __restrict__ MK0,
                                             float* __restrict__ parts) {
    __shared__ float Ws[64][64];
    __shared__ float Msub[64][65];         // padded: lanes read distinct rows
    int tid = threadIdx.x;
    int d0 = blockIdx.x * 64;              // 8 d-tiles
    int by = blockIdx.y;                   // 8 j-slices of 1024
    int dcol = tid & 63, tq = tid >> 6;
    float acc[16];
    #pragma unroll
    for (int i = 0; i < 16; ++i) acc[i] = 0.f;
    for (int sub = 0; sub < 16; ++sub) {
        int jb = by * 1024 + sub * 64;
        #pragma unroll
        for (int i = 0; i < 16; ++i) {
            int e = i * 256 + tid; int r = e >> 6, c = e & 63;
            Ws[r][c] = Wra[r * MM + jb + c];
            Msub[r][c] = MK0[(d0 + r) * MM + jb + c];
        }
        __syncthreads();
        for (int jl = 0; jl < 64; ++jl) {
            float m = Msub[dcol][jl];      // padded stride 65: conflict-free
            #pragma unroll
            for (int i = 0; i < 16; ++i) acc[i] += Ws[tq * 16 + i][jl] * m;  // broadcast
        }
        __syncthreads();
    }
    #pragma unroll
    for (int i = 0; i < 16; ++i)
        parts[(by * 64 + tq * 16 + i) * DD + d0 + dcol] = acc[i];
}

// ---------------- K4: out[t,d] = sum_p parts[p][t][d] + sum_s A[t,s] * K[s,d] ----------------
__global__ __launch_bounds__(512) void k4_final(const float* __restrict__ parts,
                                                const float* __restrict__ A,
                                                const float* __restrict__ K,
                                                float* __restrict__ out) {
    __shared__ float Arow[BB];
    int t = blockIdx.x, d = threadIdx.x;
    if (d < BB) Arow[d] = A[t * BB + d];
    __syncthreads();
    float s = 0.f;
    #pragma unroll
    for (int p = 0; p < 8; ++p) s += parts[(p * 64 + t) * DD + d];
    float s2 = 0.f;
    for (int i = 0; i < BB; ++i) s2 += Arow[i] * K[i * DD + d];
    out[t * DD + d] = s + s2;
}

extern "C" void kernel_launch(void* const* d_in, const int* in_sizes, int n_in,
                              void* d_out, int out_size, void* d_ws, size_t ws_size,
                              hipStream_t stream) {
    const float* K   = (const float*)d_in[0];   // k: [B,1,D]
    // d_in[1] = u: unused (MU never read for the output)
    const float* MK0 = (const float*)d_in[2];   // memory_knowledge: [D,M]
    // d_in[3] = memory_understanding: unused
    const float* bp  = (const float*)d_in[4];   // beta_param
    const float* gp  = (const float*)d_in[5];   // memory_gamma

    float* ws    = (float*)d_ws;
    float* G     = ws;                  // 64*64          = 4096
    float* S0    = G + 4096;            // 64*8192        = 524288
    float* n2    = S0 + 524288;         // 8192
    float* Wra   = n2 + 8192;           // 64*8192        = 524288
    float* A     = Wra + 524288;        // 64*64          = 4096
    float* parts = A + 4096;            // 8*64*512       = 262144
    float* out   = (float*)d_out;       // [B,1,D] f32

    k0_gram <<<1, 1024, 0, stream>>>(K, G);
    k1_s0   <<<128, 256, 0, stream>>>(K, MK0, S0, n2);
    k2_scan <<<1, 1024, 0, stream>>>(S0, G, n2, bp, gp, Wra, A);
    k3_u1   <<<dim3(8, 8), 256, 0, stream>>>(Wra, MK0, parts);
    k4_final<<<64, 512, 0, stream>>>(parts, A, K, out);
}

// Round 2
// 411.842 us; speedup vs baseline: 1.8056x; 1.8056x over previous
//
#include <hip/hip_runtime.h>
#include <math.h>

#define BB 64
#define DD 512
#define MM 8192
#define TPB 1024
#define CPT 8   // MM / TPB columns per thread in the scan

// ---------------- K0: G = K K^T  (G[t][s] = k_t . k_s; diag = ||k_t||^2) ----------------
__global__ __launch_bounds__(1024) void k0_gram(const float* __restrict__ K, float* __restrict__ G) {
    __shared__ float Ks[BB][129];          // +1 pad breaks the stride-128 bank collision
    int tid = threadIdx.x;
    int s = tid & 63, tq = tid >> 6;       // tq in 0..15
    float acc[4] = {0.f, 0.f, 0.f, 0.f};
    for (int d0 = 0; d0 < DD; d0 += 128) {
        #pragma unroll
        for (int i = 0; i < 8; ++i) {
            int e = i * 1024 + tid; int r = e >> 7, c = e & 127;
            Ks[r][c] = K[r * DD + d0 + c];
        }
        __syncthreads();
        for (int dl = 0; dl < 128; ++dl) {
            float kv = Ks[s][dl];          // lane-distinct rows, padded: conflict-free
            #pragma unroll
            for (int i = 0; i < 4; ++i) acc[i] += Ks[tq * 4 + i][dl] * kv;  // wave-uniform: broadcast
        }
        __syncthreads();
    }
    #pragma unroll
    for (int i = 0; i < 4; ++i) G[(tq * 4 + i) * BB + s] = acc[i];
}

// ---------------- K1: S0p[half] = K @ MK0 over a 256-d half; n2p[half] = column sumsq ----------------
__global__ __launch_bounds__(256) void k1_s0(const float* __restrict__ K, const float* __restrict__ MK0,
                                             float* __restrict__ S0p, float* __restrict__ n2p) {
    __shared__ float Ks[64][64];
    __shared__ float Ms[64][64];
    __shared__ float sq[4][64];
    int tid = threadIdx.x;
    int jb = blockIdx.x * 64;              // 128 j-blocks
    int dbase = blockIdx.y * 256;          // 2 d-halves
    int jl = tid & 63, tq = tid >> 6;
    float acc[16];
    #pragma unroll
    for (int i = 0; i < 16; ++i) acc[i] = 0.f;
    float sqa = 0.f;
    for (int dt = 0; dt < 4; ++dt) {
        int d0 = dbase + dt * 64;
        #pragma unroll
        for (int i = 0; i < 16; ++i) {
            int e = i * 256 + tid; int r = e >> 6, c = e & 63;   // c == jl always
            Ks[r][c] = K[r * DD + d0 + c];
            float m = MK0[(d0 + r) * MM + jb + c];
            Ms[r][c] = m;
            sqa += m * m;                   // per-thread partial sumsq of column jl
        }
        __syncthreads();
        for (int dl = 0; dl < 64; ++dl) {
            float mv = Ms[dl][jl];          // 2-way aliasing: free
            #pragma unroll
            for (int i = 0; i < 16; ++i) acc[i] += Ks[tq * 16 + i][dl] * mv;  // broadcast
        }
        __syncthreads();
    }
    #pragma unroll
    for (int i = 0; i < 16; ++i)
        S0p[blockIdx.y * BB * MM + (tq * 16 + i) * MM + jb + jl] = acc[i];
    sq[tq][jl] = sqa;
    __syncthreads();
    if (tq == 0) n2p[blockIdx.y * MM + jb + jl] = sq[0][jl] + sq[1][jl] + sq[2][jl] + sq[3][jl];
}

// ---------------- K2: the 64-step scan (single block, per-column state in registers) ----------------
__global__ __launch_bounds__(1024) void k2_scan(const float* __restrict__ S0p,
                                                const float* __restrict__ G,
                                                const float* __restrict__ n2p,
                                                const float* __restrict__ bp,
                                                const float* __restrict__ gp,
                                                float* __restrict__ Wra,   // [B][M]: w_r * alive(post-zero)
                                                float* __restrict__ A) {   // [B][B]: a_t[s]
    __shared__ float GAll[BB][BB];         // 16 KB
    __shared__ float PfxAll[BB][BB];       // 16 KB: Pfx[t][s] = sum_{s'=s}^{t-1} G[t][s']
    __shared__ float E[BB];                // e_t at hot column of history slot s
    __shared__ int   lastocc[BB];          // slot s is the LAST zeroing of its column (<= t)
    __shared__ float red_f[16];
    __shared__ unsigned long long red_u[16];

    const int tid = threadIdx.x;
    const int lane = tid & 63;
    const int wid = tid >> 6;

    const float beta  = 1.f / (1.f + expf(-bp[0]));
    const float gamma = gp[0];
    const float cuni  = beta / (float)MM;  // uniform write coefficient c = beta*mean(w_r), mean = 1/M
    const float omb   = 1.f - beta;

    // ---- precompute all G rows + suffix sums into LDS (once) ----
    #pragma unroll
    for (int r = 0; r < 4; ++r) {
        int t = wid * 4 + r;
        float g = G[t * BB + lane];
        GAll[t][lane] = g;
        float x = (lane < t) ? g : 0.f;
        #pragma unroll
        for (int o = 1; o < 64; o <<= 1) {
            float y = __shfl_down(x, o);
            if (lane + o < 64) x += y;
        }
        PfxAll[t][lane] = x;
    }

    float n2v[CPT], wu[CPT], alive[CPT], s0pf0[CPT], s0pf1[CPT];
    int lz[CPT];
    unsigned long long mask[CPT];          // history-slot bits owned by this column
    #pragma unroll
    for (int c = 0; c < CPT; ++c) {
        int j = c * TPB + tid;
        n2v[c] = n2p[j] + n2p[MM + j];
        wu[c] = 0.f; alive[c] = 1.f; lz[c] = 0; mask[c] = 0ull;
        s0pf0[c] = S0p[j];                 // prefetch row t=0 (both halves)
        s0pf1[c] = S0p[BB * MM + j];
    }
    if (tid < BB) lastocc[tid] = 0;
    int j0 = 0;          // argmin of all-zero w_u at t=0 is index 0 (first-index tie-break)
    int j0prev = -1;
    __syncthreads();

    for (int t = 0; t < BB; ++t) {
        // consume prefetched S0 row; issue prefetch for t+1 immediately
        float s0[CPT];
        #pragma unroll
        for (int c = 0; c < CPT; ++c) s0[c] = s0pf0[c] + s0pf1[c];
        if (t + 1 < BB) {
            #pragma unroll
            for (int c = 0; c < CPT; ++c) {
                int j = c * TPB + tid;
                s0pf0[c] = S0p[(t + 1) * MM + j];
                s0pf1[c] = S0p[(BB + t + 1) * MM + j];
            }
        }
        const float k2t  = GAll[t][t];
        const float invk = __builtin_amdgcn_rsqf(k2t);

        // ---- phase A: per-column dot/cos/e; hot-column bookkeeping ----
        float e[CPT], dot[CPT];
        float psum = 0.f;
        #pragma unroll
        for (int c = 0; c < CPT; ++c) {
            int j = c * TPB + tid;
            float d_ = alive[c] * s0[c] + cuni * PfxAll[t][lz[c]];
            float g1 = omb * GAll[t][lz[c]];
            d_ += (lz[c] >= 1) ? g1 : 0.f;                    // surviving one-hot write
            float cosv = d_ * invk * __builtin_amdgcn_rsqf(n2v[c]);
            float ee = __expf(cosv);                          // cos in [-1,1]: no max-subtract needed
            e[c] = ee; dot[c] = d_;
            psum += ee;
            if (j == j0) {                                    // this step's zeroed column
                unsigned long long mm = mask[c];
                while (mm) { int sb = __builtin_ctzll(mm); lastocc[sb] = 0; mm &= mm - 1; }
                mask[c] |= (1ull << t);
                lastocc[t] = 1;
            }
        }
        // refresh E at owned history slots with current e
        #pragma unroll
        for (int c = 0; c < CPT; ++c) {
            unsigned long long mm = mask[c];
            while (mm) { int sb = __builtin_ctzll(mm); E[sb] = e[c]; mm &= mm - 1; }
        }
        // reduce S = sum(e)
        float v = psum;
        #pragma unroll
        for (int o = 32; o > 0; o >>= 1) v += __shfl_down(v, o);
        if (lane == 0) red_f[wid] = v;
        __syncthreads();                                      // barrier 1
        float S = 0.f;
        #pragma unroll
        for (int w = 0; w < 16; ++w) S += red_f[w];
        const float invS = __builtin_amdgcn_rcpf(S);

        // ---- A row t (wave 0): a_t[s] = (c*Qe[s] + (1-b)*lastocc[s]*E[s]) / S ----
        if (tid < BB) {
            int s = tid;
            float ev = (s <= t && lastocc[s]) ? E[s] : 0.f;
            float x = ev;
            #pragma unroll
            for (int o = 1; o < 64; o <<= 1) {
                float y = __shfl_down(x, o);
                if (s + o < 64) x += y;
            }
            float suf = x - ev;            // sum over slots s' in (s, t] with lastocc
            float arow = 0.f;
            if (s < t) {
                float Qe = S - suf;
                arow = cuni * Qe;
                if (s >= 1 && lastocc[s]) arow += omb * E[s];
                arow *= invS;
            }
            A[t * BB + s] = arow;
        }

        // ---- phase B: w_u update, Wra, n2, argmin ----
        unsigned long long mymin = 0xFFFFFFFFFFFFFFFFull;
        #pragma unroll
        for (int c = 0; c < CPT; ++c) {
            int j = c * TPB + tid;
            float wr = e[c] * invS;
            // carry w_w = beta*mean + (1-beta)*onehot(j0_{t-1}) (zero at t=0; no one-hot at t=1)
            float wwold = (t == 0) ? 0.f : (cuni + ((t >= 2 && j == j0prev) ? omb : 0.f));
            float wun = gamma * wu[c] + wr + wwold;
            wu[c] = wun;
            bool isj0 = (j == j0);
            float ap = isj0 ? 0.f : alive[c];
            Wra[t * MM + j] = wr * ap;
            alive[c] = ap;
            float wwnew = cuni + ((t >= 1 && isj0) ? omb : 0.f);
            float dz = isj0 ? 0.f : dot[c];
            float nz = isj0 ? 0.f : n2v[c];
            n2v[c] = nz + 2.f * wwnew * dz + wwnew * wwnew * k2t;   // ||col + w*k||^2
            if (isj0) lz[c] = t;
            // argmin with first-index tie-break (w_u >= 0 so raw bits are order-preserving)
            unsigned long long key = ((unsigned long long)__float_as_uint(wun) << 32) | (unsigned)j;
            mymin = (key < mymin) ? key : mymin;
        }
        unsigned long long mv = mymin;
        #pragma unroll
        for (int o = 32; o > 0; o >>= 1) {
            unsigned long long ov = __shfl_down(mv, o);
            mv = (ov < mv) ? ov : mv;
        }
        if (lane == 0) red_u[wid] = mv;
        __syncthreads();                                      // barrier 2
        unsigned long long best = 0xFFFFFFFFFFFFFFFFull;
        #pragma unroll
        for (int w = 0; w < 16; ++w) { unsigned long long q = red_u[w]; best = (q < best) ? q : best; }
        j0prev = j0;
        j0 = (int)(best & 0xFFFFFFFFu);    // next step's zeroed column = this argmin
    }
}

// ---------------- K3: parts[jslice][t][d] = sum_{j in slice} Wra[t,j] * MK0[d,j] ----------------
__global__ __launch_bounds__(256) void k3_u1(const float* __restrict__ Wra, const float* __restrict__ MK0,
                                             float* __restrict__ parts) {
    __shared__ float Ws[64][64];
    __shared__ float Msub[64][65];         // padded: lanes read distinct rows
    int tid = threadIdx.x;
    int d0 = blockIdx.x * 64;              // 8 d-tiles
    int by = blockIdx.y;                   // 32 j-slices of 256
    int dcol = tid & 63, tq = tid >> 6;
    float acc[16];
    #pragma unroll
    for (int i = 0; i < 16; ++i) acc[i] = 0.f;
    for (int sub = 0; sub < 4; ++sub) {
        int jb = by * 256 + sub * 64;
        #pragma unroll
        for (int i = 0; i < 16; ++i) {
            int e = i * 256 + tid; int r = e >> 6, c = e & 63;
            Ws[r][c] = Wra[r * MM + jb + c];
            Msub[r][c] = MK0[(d0 + r) * MM + jb + c];
        }
        __syncthreads();
        for (int jl = 0; jl < 64; ++jl) {
            float m = Msub[dcol][jl];      // padded stride 65: conflict-free
            #pragma unroll
            for (int i = 0; i < 16; ++i) acc[i] += Ws[tq * 16 + i][jl] * m;  // broadcast
        }
        __syncthreads();
    }
    #pragma unroll
    for (int i = 0; i < 16; ++i)
        parts[(by * 64 + tq * 16 + i) * DD + d0 + dcol] = acc[i];
}

// ---------------- K4: out[t,d] = sum_p parts[p][t][d] + sum_s A[t,s] * K[s,d] ----------------
__global__ __launch_bounds__(512) void k4_final(const float* __restrict__ parts,
                                                const float* __restrict__ A,
                                                const float* __restrict__ K,
                                                float* __restrict__ out) {
    __shared__ float Arow[BB];
    int t = blockIdx.x, d = threadIdx.x;
    if (d < BB) Arow[d] = A[t * BB + d];
    __syncthreads();
    float s = 0.f;
    #pragma unroll
    for (int p = 0; p < 32; ++p) s += parts[(p * 64 + t) * DD + d];
    float s2 = 0.f;
    for (int i = 0; i < BB; ++i) s2 += Arow[i] * K[i * DD + d];
    out[t * DD + d] = s + s2;
}

extern "C" void kernel_launch(void* const* d_in, const int* in_sizes, int n_in,
                              void* d_out, int out_size, void* d_ws, size_t ws_size,
                              hipStream_t stream) {
    const float* K   = (const float*)d_in[0];   // k: [B,1,D]
    // d_in[1] = u: unused (MU never read for the output)
    const float* MK0 = (const float*)d_in[2];   // memory_knowledge: [D,M]
    // d_in[3] = memory_understanding: unused
    const float* bp  = (const float*)d_in[4];   // beta_param
    const float* gp  = (const float*)d_in[5];   // memory_gamma

    float* ws    = (float*)d_ws;
    float* G     = ws;                  // 64*64             = 4096
    float* S0p   = G + 4096;            // 2 * 64*8192       = 1048576
    float* n2p   = S0p + 1048576;       // 2 * 8192          = 16384
    float* Wra   = n2p + 16384;         // 64*8192           = 524288
    float* A     = Wra + 524288;        // 64*64             = 4096
    float* parts = A + 4096;            // 32*64*512         = 1048576
    float* out   = (float*)d_out;       // [B,1,D] f32

    k0_gram <<<1, 1024, 0, stream>>>(K, G);
    k1_s0   <<<dim3(128, 2), 256, 0, stream>>>(K, MK0, S0p, n2p);
    k2_scan <<<1, 1024, 0, stream>>>(S0p, G, n2p, bp, gp, Wra, A);
    k3_u1   <<<dim3(8, 32), 256, 0, stream>>>(Wra, MK0, parts);
    k4_final<<<64, 512, 0, stream>>>(parts, A, K, out);
}

// Round 3
// 405.980 us; speedup vs baseline: 1.8317x; 1.0144x over previous
//
#include <hip/hip_runtime.h>
#include <math.h>

#define BB 64
#define DD 512
#define MM 8192
#define TPB 1024
#define CPT 8   // MM / TPB columns per thread in the scan

typedef unsigned long long u64;

// ---------------- K0: G = K K^T and Pfx[t][s] = sum_{s'=s}^{t-1} G[t,s'] ----------------
__global__ __launch_bounds__(1024) void k0_gram(const float* __restrict__ K, float* __restrict__ G,
                                                float* __restrict__ Pfx) {
    __shared__ float Ks[BB][129];          // +1 pad breaks the stride-128 bank collision
    __shared__ float Gs[BB][BB];
    int tid = threadIdx.x;
    int s = tid & 63, tq = tid >> 6;       // tq in 0..15
    float acc[4] = {0.f, 0.f, 0.f, 0.f};
    for (int d0 = 0; d0 < DD; d0 += 128) {
        #pragma unroll
        for (int i = 0; i < 8; ++i) {
            int e = i * 1024 + tid; int r = e >> 7, c = e & 127;
            Ks[r][c] = K[r * DD + d0 + c];
        }
        __syncthreads();
        for (int dl = 0; dl < 128; ++dl) {
            float kv = Ks[s][dl];          // lane-distinct rows, padded: conflict-free
            #pragma unroll
            for (int i = 0; i < 4; ++i) acc[i] += Ks[tq * 4 + i][dl] * kv;  // wave-uniform: broadcast
        }
        __syncthreads();
    }
    #pragma unroll
    for (int i = 0; i < 4; ++i) {
        G[(tq * 4 + i) * BB + s] = acc[i];
        Gs[tq * 4 + i][s] = acc[i];
    }
    __syncthreads();
    // suffix sums: wave tq handles rows tq*4 .. tq*4+3, lane = s
    #pragma unroll
    for (int r = 0; r < 4; ++r) {
        int row = tq * 4 + r;
        float x = (s < row) ? Gs[row][s] : 0.f;
        #pragma unroll
        for (int o = 1; o < 64; o <<= 1) {
            float y = __shfl_down(x, o);
            if (s + o < 64) x += y;
        }
        Pfx[row * BB + s] = x;
    }
}

// ---------------- K1: S0p[half] = K @ MK0 over a 256-d half; n2p[half] = column sumsq ----------------
// (verbatim from R2 -- keeps S0 bit-identical)
__global__ __launch_bounds__(256) void k1_s0(const float* __restrict__ K, const float* __restrict__ MK0,
                                             float* __restrict__ S0p, float* __restrict__ n2p) {
    __shared__ float Ks[64][64];
    __shared__ float Ms[64][64];
    __shared__ float sq[4][64];
    int tid = threadIdx.x;
    int jb = blockIdx.x * 64;              // 128 j-blocks
    int dbase = blockIdx.y * 256;          // 2 d-halves
    int jl = tid & 63, tq = tid >> 6;
    float acc[16];
    #pragma unroll
    for (int i = 0; i < 16; ++i) acc[i] = 0.f;
    float sqa = 0.f;
    for (int dt = 0; dt < 4; ++dt) {
        int d0 = dbase + dt * 64;
        #pragma unroll
        for (int i = 0; i < 16; ++i) {
            int e = i * 256 + tid; int r = e >> 6, c = e & 63;   // c == jl always
            Ks[r][c] = K[r * DD + d0 + c];
            float m = MK0[(d0 + r) * MM + jb + c];
            Ms[r][c] = m;
            sqa += m * m;                   // per-thread partial sumsq of column jl
        }
        __syncthreads();
        for (int dl = 0; dl < 64; ++dl) {
            float mv = Ms[dl][jl];          // 2-way aliasing: free
            #pragma unroll
            for (int i = 0; i < 16; ++i) acc[i] += Ks[tq * 16 + i][dl] * mv;  // broadcast
        }
        __syncthreads();
    }
    #pragma unroll
    for (int i = 0; i < 16; ++i)
        S0p[blockIdx.y * BB * MM + (tq * 16 + i) * MM + jb + jl] = acc[i];
    sq[tq][jl] = sqa;
    __syncthreads();
    if (tq == 0) n2p[blockIdx.y * MM + jb + jl] = sq[0][jl] + sq[1][jl] + sq[2][jl] + sq[3][jl];
}

// ---------------- K1b: cold-hypothesis E matrix, fully parallel over (t ext.) columns ----------------
// Ecold[t][j] = exp( dot_t / (|k_t| * sqrt(n2cold_t)) ), dot_t = S0[t,j] + c*Pfx[t][0]
__global__ __launch_bounds__(256) void k1b_ecold(const float* __restrict__ S0p,
                                                 const float* __restrict__ G,
                                                 const float* __restrict__ Pfx,
                                                 const float* __restrict__ n2p,
                                                 const float* __restrict__ bp,
                                                 float* __restrict__ Ecold) {
    __shared__ float Pfx0s[BB], invks[BB], k2s[BB];
    int tid = threadIdx.x;
    int j = blockIdx.x * 256 + tid;        // 32 blocks x 256 = 8192 columns
    if (tid < BB) {
        float g = G[tid * BB + tid];
        k2s[tid] = g;
        invks[tid] = __builtin_amdgcn_rsqf(g);
        Pfx0s[tid] = Pfx[tid * BB + 0];
    }
    const float beta = 1.f / (1.f + expf(-bp[0]));
    const float cuni = beta / (float)MM;
    float n2c = n2p[j] + n2p[MM + j];
    __syncthreads();
    for (int t = 0; t < BB; ++t) {
        float s0 = S0p[t * MM + j] + S0p[(BB + t) * MM + j];
        float d_ = s0 + cuni * Pfx0s[t];                 // cold: alive=1, lz=0, no one-hot term
        float cosv = d_ * invks[t] * __builtin_amdgcn_rsqf(n2c);
        float ee = __expf(cosv);
        Ecold[t * MM + j] = ee;
        n2c = n2c + 2.f * cuni * d_ + cuni * cuni * k2s[t];   // same expr order as R2 phase B (cold)
    }
}

// ---------------- KS: Scold[t] = sum_j Ecold[t][j] (deterministic tree) ----------------
__global__ __launch_bounds__(256) void ks_rowsum(const float* __restrict__ Ecold, float* __restrict__ Scold) {
    __shared__ float sw[4];
    int t = blockIdx.x, tid = threadIdx.x;
    int lane = tid & 63, wid = tid >> 6;
    float s = 0.f;
    #pragma unroll
    for (int i = 0; i < 32; ++i) s += Ecold[t * MM + i * 256 + tid];
    #pragma unroll
    for (int o = 32; o > 0; o >>= 1) s += __shfl_down(s, o);
    if (lane == 0) sw[wid] = s;
    __syncthreads();
    if (tid == 0) Scold[t] = sw[0] + sw[1] + sw[2] + sw[3];
}

// ---------------- K2: the 64-step scan -- hot columns + reductions only ----------------
__global__ __launch_bounds__(1024) void k2_scan(const float* __restrict__ Ecold,
                                                const float* __restrict__ G,
                                                const float* __restrict__ Pfx,
                                                const float* __restrict__ Scoldg,
                                                const float* __restrict__ bp,
                                                const float* __restrict__ gp,
                                                float* __restrict__ A,      // [B][B]
                                                float* __restrict__ Dcolg,  // [B][64] hot corrections
                                                int*   __restrict__ hcolg,  // [64] hot column ids
                                                float* __restrict__ invSg) {// [B]
    __shared__ float GAll[BB * BB];
    __shared__ float PfxAll[BB * BB];
    __shared__ float Scold[BB];
    __shared__ float E[BB];          // true e at history-slot columns
    __shared__ float DeltaL[BB];     // e_true - Ecold per hot index
    __shared__ float EcHot[BB];      // Ecold at hot columns (current step)
    __shared__ int   lastocc[BB];
    __shared__ int   hcolL[BB];
    __shared__ int   nhotL;
    __shared__ u64   minL[2];

    const int tid = threadIdx.x;
    const int lane = tid & 63;
    const int wid = tid >> 6;

    const float beta  = 1.f / (1.f + expf(-bp[0]));
    const float gamma = gp[0];
    const float cuni  = beta / (float)MM;
    const float omb   = 1.f - beta;

    #pragma unroll
    for (int i = 0; i < 4; ++i) {
        GAll[i * 1024 + tid] = G[i * 1024 + tid];
        PfxAll[i * 1024 + tid] = Pfx[i * 1024 + tid];
    }
    if (tid < BB) {
        Scold[tid] = Scoldg[tid];
        E[tid] = 0.f; DeltaL[tid] = 0.f; EcHot[tid] = 0.f;
        lastocc[tid] = 0; hcolL[tid] = 0;
    }
    if (tid == 0) { nhotL = 0; minL[0] = ~0ull; minL[1] = ~0ull; }

    float wu[CPT], et[CPT], n2v[CPT], ecur[CPT], epf[CPT];
    int lz[CPT], hidx[CPT];
    u64 mask[CPT];
    int hotm = 0;
    #pragma unroll
    for (int c = 0; c < CPT; ++c) {
        wu[c] = 0.f; et[c] = 0.f; n2v[c] = 0.f; lz[c] = 0; hidx[c] = 0; mask[c] = 0ull;
        epf[c] = Ecold[c * TPB + tid];
    }
    int j0prev = -1;
    __syncthreads();

    for (int t = 0; t < BB; ++t) {
        const int j0 = (t == 0) ? 0 : (int)(minL[t & 1] & 0xFFFFFFFFu);
        #pragma unroll
        for (int c = 0; c < CPT; ++c) ecur[c] = epf[c];
        if (t + 1 < BB) {
            #pragma unroll
            for (int c = 0; c < CPT; ++c) epf[c] = Ecold[(t + 1) * MM + c * TPB + tid];
        }
        const float k2t  = GAll[t * BB + t];
        const float invk = __builtin_amdgcn_rsqf(k2t);

        // ---- phase A: hot columns + zeroing bookkeeping ----
        const bool own = ((j0 & (TPB - 1)) == tid);
        const int  cown = j0 >> 10;
        if (hotm || own) {
            #pragma unroll
            for (int c = 0; c < CPT; ++c) {
                bool hot  = (hotm >> c) & 1;
                bool isj0 = own && (c == cown);
                if (!(hot || isj0)) continue;
                if (hot) {
                    int l = lz[c];
                    float d_ = cuni * PfxAll[t * BB + l];      // alive=0: no S0 term
                    float g1 = omb * GAll[t * BB + l];
                    d_ += (l >= 1) ? g1 : 0.f;
                    float cosv = d_ * invk * __builtin_amdgcn_rsqf(n2v[c]);
                    float ev = __expf(cosv);
                    et[c] = ev;
                    int hi = hidx[c];
                    DeltaL[hi] = ev - ecur[c];
                    EcHot[hi]  = ecur[c];
                    u64 mm = mask[c];
                    while (mm) { int sb = __builtin_ctzll(mm); E[sb] = ev; mm &= mm - 1; }
                    if (!isj0) n2v[c] = n2v[c] + 2.f * cuni * d_ + cuni * cuni * k2t;
                }
                if (isj0) {
                    if (!hot) {                    // fresh zeroing: allocate hot index
                        int i = nhotL;
                        hcolL[i] = j0; hidx[c] = i; nhotL = i + 1;
                        et[c] = ecur[c];           // pre-zero e == cold value this step
                        EcHot[i] = ecur[c];        // DeltaL[i] stays 0
                    }
                    u64 mm = mask[c];
                    while (mm) { int sb = __builtin_ctzll(mm); lastocc[sb] = 0; mm &= mm - 1; }
                    mask[c] |= (1ull << t);
                    lastocc[t] = 1;
                    E[t] = et[c];
                    lz[c] = t;
                    hotm |= (1 << c);
                    float ww0 = cuni + ((t >= 1) ? omb : 0.f);
                    n2v[c] = ww0 * ww0 * k2t;      // zeroed then written
                }
            }
        }
        if (tid == 0) minL[(t + 1) & 1] = ~0ull;   // reset next-step argmin slot
        __syncthreads();                           // barrier 1

        // ---- S (all waves redundantly; no extra barrier) ----
        float dl = DeltaL[lane];
        #pragma unroll
        for (int o = 1; o < 64; o <<= 1) dl += __shfl_xor(dl, o);
        const float S = Scold[t] + dl;
        const float invS = __builtin_amdgcn_rcpf(S);

        // ---- wave 0: A row, Dcol row, invS dump ----
        if (wid == 0) {
            int s = lane;
            float ev = (s <= t && lastocc[s]) ? E[s] : 0.f;
            float x = ev;
            #pragma unroll
            for (int o = 1; o < 64; o <<= 1) {
                float y = __shfl_down(x, o);
                if (s + o < 64) x += y;
            }
            float suf = x - ev;
            float arow = 0.f;
            if (s < t) {
                float Qe = S - suf;
                arow = cuni * Qe;
                if (s >= 1 && lastocc[s]) arow += omb * E[s];
                arow *= invS;
            }
            A[t * BB + s] = arow;
            float dv = (lane < nhotL) ? (-invS * EcHot[lane]) : 0.f;
            Dcolg[t * BB + lane] = dv;
            if (lane == 0) invSg[t] = invS;
        }

        // ---- phase C: w_u update + argmin (needs only invS, computed per-wave) ----
        const float wwoldc = (t == 0) ? 0.f : cuni;
        u64 mymin = ~0ull;
        #pragma unroll
        for (int c = 0; c < CPT; ++c) {
            int j = c * TPB + tid;
            float eae = ((hotm >> c) & 1) ? et[c] : ecur[c];
            float wwold = wwoldc + ((t >= 2 && j == j0prev) ? omb : 0.f);
            float wun = gamma * wu[c] + eae * invS + wwold;
            wu[c] = wun;
            u64 key = (((u64)__float_as_uint(wun)) << 32) | (unsigned)j;
            mymin = (key < mymin) ? key : mymin;
        }
        #pragma unroll
        for (int o = 32; o > 0; o >>= 1) {
            u64 ov = __shfl_down(mymin, o);
            mymin = (ov < mymin) ? ov : mymin;
        }
        if (lane == 0) atomicMin(&minL[(t + 1) & 1], mymin);
        j0prev = j0;
        __syncthreads();                           // barrier 2
    }
    if (tid < BB) hcolg[tid] = hcolL[tid];
}

// ---------------- K3: parts[jslice][t][d] = sum_{j in slice} Ecold[t,j] * MK0[d,j] ----------------
// (verbatim R2 structure; input is now the UNSCALED cold E matrix -- invS applied in k4)
__global__ __launch_bounds__(256) void k3_u1(const float* __restrict__ Ecold, const float* __restrict__ MK0,
                                             float* __restrict__ parts) {
    __shared__ float Ws[64][64];
    __shared__ float Msub[64][65];
    int tid = threadIdx.x;
    int d0 = blockIdx.x * 64;              // 8 d-tiles
    int by = blockIdx.y;                   // 32 j-slices of 256
    int dcol = tid & 63, tq = tid >> 6;
    float acc[16];
    #pragma unroll
    for (int i = 0; i < 16; ++i) acc[i] = 0.f;
    for (int sub = 0; sub < 4; ++sub) {
        int jb = by * 256 + sub * 64;
        #pragma unroll
        for (int i = 0; i < 16; ++i) {
            int e = i * 256 + tid; int r = e >> 6, c = e & 63;
            Ws[r][c] = Ecold[r * MM + jb + c];
            Msub[r][c] = MK0[(d0 + r) * MM + jb + c];
        }
        __syncthreads();
        for (int jl = 0; jl < 64; ++jl) {
            float m = Msub[dcol][jl];
            #pragma unroll
            for (int i = 0; i < 16; ++i) acc[i] += Ws[tq * 16 + i][jl] * m;
        }
        __syncthreads();
    }
    #pragma unroll
    for (int i = 0; i < 16; ++i)
        parts[(by * 64 + tq * 16 + i) * DD + d0 + dcol] = acc[i];
}

// ---------------- K3b: gather hot columns of MK0 into row-major MKhot[i][d] ----------------
__global__ __launch_bounds__(512) void k3b_gather(const float* __restrict__ MK0, const int* __restrict__ hcolg,
                                                  float* __restrict__ MKhot) {
    int i = blockIdx.x, d = threadIdx.x;
    int h = hcolg[i];
    MKhot[i * DD + d] = MK0[d * MM + h];
}

// ---------------- K4: out[t,d] = invS[t]*sum_p parts + sum_i Dcol[t,i]*MKhot[i,d] + sum_s A[t,s]*K[s,d] ----------------
__global__ __launch_bounds__(512) void k4_final(const float* __restrict__ parts,
                                                const float* __restrict__ A,
                                                const float* __restrict__ K,
                                                const float* __restrict__ Dcolg,
                                                const float* __restrict__ MKhot,
                                                const float* __restrict__ invSg,
                                                float* __restrict__ out) {
    __shared__ float Arow[BB];
    __shared__ float Drow[BB];
    int t = blockIdx.x, d = threadIdx.x;
    if (d < BB) { Arow[d] = A[t * BB + d]; Drow[d] = Dcolg[t * BB + d]; }
    __syncthreads();
    float isv = invSg[t];
    float s1 = 0.f;
    #pragma unroll
    for (int p = 0; p < 32; ++p) s1 += parts[(p * 64 + t) * DD + d];
    float s2 = 0.f;
    for (int i = 0; i < BB; ++i) s2 += Drow[i] * MKhot[i * DD + d];
    float s3 = 0.f;
    for (int i = 0; i < BB; ++i) s3 += Arow[i] * K[i * DD + d];
    out[t * DD + d] = isv * s1 + s2 + s3;
}

extern "C" void kernel_launch(void* const* d_in, const int* in_sizes, int n_in,
                              void* d_out, int out_size, void* d_ws, size_t ws_size,
                              hipStream_t stream) {
    const float* K   = (const float*)d_in[0];   // k: [B,1,D]
    // d_in[1] = u: unused (MU never read for the output)
    const float* MK0 = (const float*)d_in[2];   // memory_knowledge: [D,M]
    // d_in[3] = memory_understanding: unused
    const float* bp  = (const float*)d_in[4];   // beta_param
    const float* gp  = (const float*)d_in[5];   // memory_gamma

    float* ws    = (float*)d_ws;
    float* G     = ws;                  // 4096
    float* Pfx   = G + 4096;            // 4096
    float* S0p   = Pfx + 4096;          // 2*64*8192 = 1048576
    float* n2p   = S0p + 1048576;       // 2*8192    = 16384
    float* Ecold = n2p + 16384;         // 64*8192   = 524288
    float* Scold = Ecold + 524288;      // 64
    float* A     = Scold + 64;          // 4096
    float* Dcol  = A + 4096;            // 4096
    float* invS  = Dcol + 4096;         // 64
    float* MKhot = invS + 64;           // 64*512    = 32768
    float* parts = MKhot + 32768;       // 32*64*512 = 1048576
    int*   hcol  = (int*)(parts + 1048576); // 64 ints
    float* out   = (float*)d_out;       // [B,1,D] f32

    k0_gram   <<<1, 1024, 0, stream>>>(K, G, Pfx);
    k1_s0     <<<dim3(128, 2), 256, 0, stream>>>(K, MK0, S0p, n2p);
    k1b_ecold <<<32, 256, 0, stream>>>(S0p, G, Pfx, n2p, bp, Ecold);
    ks_rowsum <<<64, 256, 0, stream>>>(Ecold, Scold);
    k2_scan   <<<1, 1024, 0, stream>>>(Ecold, G, Pfx, Scold, bp, gp, A, Dcol, hcol, invS);
    k3_u1     <<<dim3(8, 32), 256, 0, stream>>>(Ecold, MK0, parts);
    k3b_gather<<<64, 512, 0, stream>>>(MK0, hcol, MKhot);
    k4_final  <<<64, 512, 0, stream>>>(parts, A, K, Dcol, MKhot, invS, out);
}

// Round 4
// 353.283 us; speedup vs baseline: 2.1049x; 1.1492x over previous
//
#include <hip/hip_runtime.h>
#include <math.h>

#define BB 64
#define DD 512
#define MM 8192
#define TPB 1024
#define CPT 8   // MM / TPB columns per thread in the scan

typedef unsigned long long u64;

// ---------------- K0: G = K K^T and Pfx[t][s] = sum_{s'=s}^{t-1} G[t,s'] ----------------
__global__ __launch_bounds__(1024) void k0_gram(const float* __restrict__ K, float* __restrict__ G,
                                                float* __restrict__ Pfx) {
    __shared__ float Ks[BB][129];          // +1 pad breaks the stride-128 bank collision
    __shared__ float Gs[BB][BB];
    int tid = threadIdx.x;
    int s = tid & 63, tq = tid >> 6;       // tq in 0..15
    float acc[4] = {0.f, 0.f, 0.f, 0.f};
    for (int d0 = 0; d0 < DD; d0 += 128) {
        #pragma unroll
        for (int i = 0; i < 8; ++i) {
            int e = i * 1024 + tid; int r = e >> 7, c = e & 127;
            Ks[r][c] = K[r * DD + d0 + c];
        }
        __syncthreads();
        for (int dl = 0; dl < 128; ++dl) {
            float kv = Ks[s][dl];          // lane-distinct rows, padded: conflict-free
            #pragma unroll
            for (int i = 0; i < 4; ++i) acc[i] += Ks[tq * 4 + i][dl] * kv;  // wave-uniform: broadcast
        }
        __syncthreads();
    }
    #pragma unroll
    for (int i = 0; i < 4; ++i) {
        G[(tq * 4 + i) * BB + s] = acc[i];
        Gs[tq * 4 + i][s] = acc[i];
    }
    __syncthreads();
    // suffix sums: wave tq handles rows tq*4 .. tq*4+3, lane = s
    #pragma unroll
    for (int r = 0; r < 4; ++r) {
        int row = tq * 4 + r;
        float x = (s < row) ? Gs[row][s] : 0.f;
        #pragma unroll
        for (int o = 1; o < 64; o <<= 1) {
            float y = __shfl_down(x, o);
            if (s + o < 64) x += y;
        }
        Pfx[row * BB + s] = x;
    }
}

// ---------------- K1: S0p[half] = K @ MK0 over a 256-d half; n2p[half] = column sumsq ----------------
// 4x4 ownership (t4 x strided j) so LDS reads merge into ds_read2; fma order per acc unchanged.
__global__ __launch_bounds__(256) void k1_s0(const float* __restrict__ K, const float* __restrict__ MK0,
                                             float* __restrict__ S0p, float* __restrict__ n2p) {
    __shared__ float Ks[64 * 65];          // [t-row][dl], stride 65
    __shared__ float Ms[64 * 65];          // [dl][j],     stride 65
    __shared__ float sq[4 * 64];
    const int tid = threadIdx.x;
    const int lane = tid & 63, w = tid >> 6;
    const int jb = blockIdx.x * 64;        // 128 j-blocks
    const int dbase = blockIdx.y * 256;    // 2 d-halves
    const int t4 = ((w << 2) | (lane >> 4)) << 2;  // 0,4,...,60
    const int jq0 = lane & 15;
    float acc[4][4];
    #pragma unroll
    for (int i = 0; i < 4; ++i)
        #pragma unroll
        for (int q = 0; q < 4; ++q) acc[i][q] = 0.f;
    float sqa = 0.f;
    for (int dt = 0; dt < 4; ++dt) {
        int d0 = dbase + dt * 64;
        #pragma unroll
        for (int i = 0; i < 16; ++i) {
            int e = i * 256 + tid; int r = e >> 6, c = e & 63;
            Ks[r * 65 + c] = K[r * DD + d0 + c];
            float m = MK0[(d0 + r) * MM + jb + c];
            Ms[r * 65 + c] = m;
            sqa += m * m;                  // same element set & order as before: n2p bit-identical
        }
        __syncthreads();
        #pragma unroll 4
        for (int dl = 0; dl < 64; ++dl) {
            float kv[4], mv[4];
            #pragma unroll
            for (int i = 0; i < 4; ++i) kv[i] = Ks[(t4 + i) * 65 + dl];
            #pragma unroll
            for (int q = 0; q < 4; ++q) mv[q] = Ms[dl * 65 + jq0 + 16 * q];
            #pragma unroll
            for (int i = 0; i < 4; ++i)
                #pragma unroll
                for (int q = 0; q < 4; ++q) acc[i][q] += kv[i] * mv[q];
        }
        __syncthreads();
    }
    #pragma unroll
    for (int i = 0; i < 4; ++i)
        #pragma unroll
        for (int q = 0; q < 4; ++q)
            S0p[blockIdx.y * BB * MM + (t4 + i) * MM + jb + jq0 + 16 * q] = acc[i][q];
    sq[w * 64 + lane] = sqa;
    __syncthreads();
    if (w == 0) n2p[blockIdx.y * MM + jb + lane] =
        sq[lane] + sq[64 + lane] + sq[128 + lane] + sq[192 + lane];
}

// ---------------- K1b: cold-hypothesis E matrix, fully parallel over columns ----------------
__global__ __launch_bounds__(256) void k1b_ecold(const float* __restrict__ S0p,
                                                 const float* __restrict__ G,
                                                 const float* __restrict__ Pfx,
                                                 const float* __restrict__ n2p,
                                                 const float* __restrict__ bp,
                                                 float* __restrict__ Ecold) {
    __shared__ float Pfx0s[BB], invks[BB], k2s[BB];
    int tid = threadIdx.x;
    int j = blockIdx.x * 256 + tid;        // 32 blocks x 256 = 8192 columns
    if (tid < BB) {
        float g = G[tid * BB + tid];
        k2s[tid] = g;
        invks[tid] = __builtin_amdgcn_rsqf(g);
        Pfx0s[tid] = Pfx[tid * BB + 0];
    }
    const float beta = 1.f / (1.f + expf(-bp[0]));
    const float cuni = beta / (float)MM;
    float n2c = n2p[j] + n2p[MM + j];
    __syncthreads();
    for (int t = 0; t < BB; ++t) {
        float s0 = S0p[t * MM + j] + S0p[(BB + t) * MM + j];
        float d_ = s0 + cuni * Pfx0s[t];                 // cold: alive=1, lz=0, no one-hot term
        float cosv = d_ * invks[t] * __builtin_amdgcn_rsqf(n2c);
        float ee = __expf(cosv);
        Ecold[t * MM + j] = ee;
        n2c = n2c + 2.f * cuni * d_ + cuni * cuni * k2s[t];
    }
}

// ---------------- KS: Scold[t] = sum_j Ecold[t][j] (deterministic tree) ----------------
__global__ __launch_bounds__(256) void ks_rowsum(const float* __restrict__ Ecold, float* __restrict__ Scold) {
    __shared__ float sw[4];
    int t = blockIdx.x, tid = threadIdx.x;
    int lane = tid & 63, wid = tid >> 6;
    float s = 0.f;
    #pragma unroll
    for (int i = 0; i < 32; ++i) s += Ecold[t * MM + i * 256 + tid];
    #pragma unroll
    for (int o = 32; o > 0; o >>= 1) s += __shfl_down(s, o);
    if (lane == 0) sw[wid] = s;
    __syncthreads();
    if (tid == 0) Scold[t] = sw[0] + sw[1] + sw[2] + sw[3];
}

// ---------------- K2: 64-step scan, ONE barrier per step, lane-replicated hot slots ----------------
__global__ __launch_bounds__(1024) void k2_scan(const float* __restrict__ Ecold,
                                                const float* __restrict__ G,
                                                const float* __restrict__ Pfx,
                                                const float* __restrict__ Scoldg,
                                                const float* __restrict__ bp,
                                                const float* __restrict__ gp,
                                                float* __restrict__ A,      // [B][B]
                                                float* __restrict__ Dcolg,  // [B][64] hot corrections
                                                int*   __restrict__ hcolg,  // [64] hot column ids (by step)
                                                float* __restrict__ invSg) {// [B]
    __shared__ float GAll[BB * BB];
    __shared__ float PfxAll[BB * BB];
    __shared__ float ScoldL[BB];
    __shared__ u64 red_u[2][16];     // double-buffered wave-partial argmins

    const int tid = threadIdx.x;
    const int lane = tid & 63;
    const int wid = tid >> 6;

    const float beta  = 1.f / (1.f + expf(-bp[0]));
    const float gamma = gp[0];
    const float cuni  = beta / (float)MM;
    const float omb   = 1.f - beta;

    #pragma unroll
    for (int i = 0; i < 4; ++i) {
        GAll[i * 1024 + tid] = G[i * 1024 + tid];
        PfxAll[i * 1024 + tid] = Pfx[i * 1024 + tid];
    }
    if (tid < BB) ScoldL[tid] = Scoldg[tid];

    // thread-local cold + hot state (for the w_u / argmin over this thread's 8 columns)
    float wu[CPT], ecur[CPT], epf[CPT], ett[CPT], n2t[CPT];
    int lzt[CPT];
    int hotm = 0;
    #pragma unroll
    for (int c = 0; c < CPT; ++c) {
        wu[c] = 0.f; ett[c] = 0.f; n2t[c] = 0.f; lzt[c] = 0;
        epf[c] = Ecold[c * TPB + tid];
    }

    // lane-replicated slot state: slot s == lane, created at step s (replicated in every wave)
    float slot_n2 = 0.f, slot_E = 0.f, slot_ec = 0.f, slot_ecpf = 0.f;
    int   slot_j = -1;
    bool  slot_act = false;          // == lastocc

    int j0prev = -1;
    __syncthreads();

    for (int t = 0; t < BB; ++t) {
        // ---- 1. combine wave-partial argmins -> j0 (every wave, no 2nd barrier) ----
        int j0;
        if (t == 0) j0 = 0;          // all-zero w_u: first index
        else {
            u64 pm = red_u[t & 1][lane & 15];
            #pragma unroll
            for (int o = 1; o < 16; o <<= 1) {
                u64 q = __shfl_xor(pm, o);
                pm = (q < pm) ? q : pm;
            }
            j0 = (int)(pm & 0xFFFFFFFFu);
        }

        // ---- 2. cold prefetch for next step's phase C (completes at the barrier drain) ----
        #pragma unroll
        for (int c = 0; c < CPT; ++c) ecur[c] = epf[c];
        if (t + 1 < BB) {
            #pragma unroll
            for (int c = 0; c < CPT; ++c) epf[c] = Ecold[(t + 1) * MM + c * TPB + tid];
        }

        const float k2t  = GAll[t * BB + t];
        const float invk = __builtin_amdgcn_rsqf(k2t);

        // ---- 3. supersession ballot (before slot t exists) ----
        u64 sup = __ballot(slot_act && (slot_j == j0));
        const bool has_sup = (sup != 0ull);
        const int  ssup = has_sup ? __builtin_ctzll(sup) : 0;

        // ---- 4. hot-lane update: pre-zero true e, Delta vs cold, n2 advance ----
        float myDelta = 0.f, e_true = 0.f;
        if (slot_act) {
            float d_ = cuni * PfxAll[t * BB + lane];
            if (lane >= 1) d_ += omb * GAll[t * BB + lane];
            e_true = __expf(d_ * invk * __builtin_amdgcn_rsqf(slot_n2));
            myDelta = e_true - slot_ec;      // slot_ec = Ecold[t][slot_j], prefetched last step
            slot_E = e_true;
            slot_n2 = slot_n2 + 2.f * cuni * d_ + cuni * cuni * k2t;
        }

        // ---- 5. create slot t; handle re-zeroing ----
        if (lane == t) {
            slot_j = j0;
            float ww0 = cuni + ((t >= 1) ? omb : 0.f);
            slot_n2 = ww0 * ww0 * k2t;       // zeroed then written
            slot_act = true;
            float latev = Ecold[t * MM + j0];  // late load: off the S critical path (Delta_t = 0)
            slot_ec = latev;                  // for Dcol this step
            slot_E = latev;                   // pre-zero e (cold case)
        }
        if (has_sup) {
            float evs = __shfl(e_true, ssup);
            if (lane == t) slot_E = evs;      // pre-zero e of a re-zeroed hot column
            if (lane == ssup) slot_act = false;  // superseded (after its Delta was captured)
        }
        if (t + 1 < BB && slot_act) slot_ecpf = Ecold[(t + 1) * MM + slot_j];

        // ---- 6. S and invS (all waves, registers + shuffles only) ----
        float dsum = myDelta;
        #pragma unroll
        for (int o = 1; o < 64; o <<= 1) dsum += __shfl_xor(dsum, o);
        const float S = ScoldL[t] + dsum;
        const float invS = __builtin_amdgcn_rcpf(S);

        // ---- 7. wave 0: A row, Dcol row, invS ----
        if (wid == 0) {
            float Ev = slot_E;
            bool act = slot_act;             // lanes s>t are inactive
            float ev = act ? Ev : 0.f;
            float x = ev;
            #pragma unroll
            for (int o = 1; o < 64; o <<= 1) {
                float y = __shfl_down(x, o);
                if (lane + o < 64) x += y;
            }
            float suf = x - ev;              // sum over slots s' in (s, t] with lastocc
            float arow = 0.f;
            if (lane < t) {
                float Qe = S - suf;
                arow = cuni * Qe;
                if (lane >= 1 && act) arow += omb * Ev;
                arow *= invS;
            }
            A[t * BB + lane] = arow;
            Dcolg[t * BB + lane] = act ? (-invS * slot_ec) : 0.f;
            if (lane == 0) invSg[t] = invS;
        }

        // ---- 8. thread-local hot updates (for this thread's own hot columns) ----
        const bool own = ((j0 & (TPB - 1)) == tid);
        const int  cown = j0 >> 10;
        if (hotm || own) {
            #pragma unroll
            for (int c = 0; c < CPT; ++c) {
                bool hot  = (hotm >> c) & 1;
                bool isj0 = own && (c == cown);
                if (!(hot || isj0)) continue;
                if (hot) {
                    int l = lzt[c];
                    float d_ = cuni * PfxAll[t * BB + l];
                    if (l >= 1) d_ += omb * GAll[t * BB + l];
                    float ev = __expf(d_ * invk * __builtin_amdgcn_rsqf(n2t[c]));
                    ett[c] = ev;
                    if (!isj0) n2t[c] = n2t[c] + 2.f * cuni * d_ + cuni * cuni * k2t;
                }
                if (isj0) {
                    if (!hot) ett[c] = ecur[c];   // fresh zeroing: pre-zero e == cold
                    lzt[c] = t;
                    hotm |= (1 << c);
                    float ww0 = cuni + ((t >= 1) ? omb : 0.f);
                    n2t[c] = ww0 * ww0 * k2t;
                }
            }
        }

        // ---- 9. phase C: w_u fma + min + index, wave partial ----
        const float wwoldc = (t == 0) ? 0.f : cuni;
        float tmin = 0.f;
        #pragma unroll
        for (int c = 0; c < CPT; ++c) {
            int j = c * TPB + tid;
            float eae = ((hotm >> c) & 1) ? ett[c] : ecur[c];
            float wwold = wwoldc + ((t >= 2 && j == j0prev) ? omb : 0.f);
            float wun = gamma * wu[c] + eae * invS + wwold;
            wu[c] = wun;
            tmin = (c == 0) ? wun : fminf(tmin, wun);
        }
        int cbest = CPT - 1;
        #pragma unroll
        for (int c = CPT - 2; c >= 0; --c) cbest = (wu[c] == tmin) ? c : cbest; // first-index tie-break
        u64 key = (((u64)__float_as_uint(tmin)) << 32) | (unsigned)(cbest * TPB + tid);
        #pragma unroll
        for (int o = 1; o < 64; o <<= 1) {
            u64 q = __shfl_xor(key, o);
            key = (q < key) ? q : key;
        }
        if (lane == 0) red_u[(t + 1) & 1][wid] = key;

        // ---- 10. advance ----
        if (slot_act) slot_ec = slot_ecpf;
        j0prev = j0;
        __syncthreads();                 // the ONE barrier: also drains all prefetches
    }
    if (wid == 0) hcolg[lane] = slot_j;  // slot s holds j0_s
}

// ---------------- K3: parts[jslice][t][d] = sum_{j in slice} Ecold[t,j] * MK0[d,j] ----------------
__global__ __launch_bounds__(256) void k3_u1(const float* __restrict__ Ecold, const float* __restrict__ MK0,
                                             float* __restrict__ parts) {
    __shared__ float Ws[64 * 65];        // [t][j-local]
    __shared__ float Msub[64 * 65];      // [d-local][j-local]
    const int tid = threadIdx.x;
    const int lane = tid & 63, w = tid >> 6;
    const int d0 = blockIdx.x * 64;      // 8 d-tiles
    const int by = blockIdx.y;           // 32 j-slices of 256
    const int t4 = ((w << 2) | (lane >> 4)) << 2;
    const int dq0 = lane & 15;
    float acc[4][4];
    #pragma unroll
    for (int i = 0; i < 4; ++i)
        #pragma unroll
        for (int q = 0; q < 4; ++q) acc[i][q] = 0.f;
    for (int sub = 0; sub < 4; ++sub) {
        int jb = by * 256 + sub * 64;
        #pragma unroll
        for (int i = 0; i < 16; ++i) {
            int e = i * 256 + tid; int r = e >> 6, c = e & 63;
            Ws[r * 65 + c] = Ecold[r * MM + jb + c];
            Msub[r * 65 + c] = MK0[(d0 + r) * MM + jb + c];
        }
        __syncthreads();
        #pragma unroll 4
        for (int jl = 0; jl < 64; ++jl) {
            float wv[4], mv[4];
            #pragma unroll
            for (int i = 0; i < 4; ++i) wv[i] = Ws[(t4 + i) * 65 + jl];
            #pragma unroll
            for (int q = 0; q < 4; ++q) mv[q] = Msub[(dq0 + 16 * q) * 65 + jl];
            #pragma unroll
            for (int i = 0; i < 4; ++i)
                #pragma unroll
                for (int q = 0; q < 4; ++q) acc[i][q] += wv[i] * mv[q];
        }
        __syncthreads();
    }
    #pragma unroll
    for (int i = 0; i < 4; ++i)
        #pragma unroll
        for (int q = 0; q < 4; ++q)
            parts[(by * 64 + t4 + i) * DD + d0 + dq0 + 16 * q] = acc[i][q];
}

// ---------------- K3b: gather hot columns of MK0 into row-major MKhot[s][d] ----------------
__global__ __launch_bounds__(512) void k3b_gather(const float* __restrict__ MK0, const int* __restrict__ hcolg,
                                                  float* __restrict__ MKhot) {
    int i = blockIdx.x, d = threadIdx.x;
    int h = hcolg[i];
    MKhot[i * DD + d] = MK0[d * MM + h];
}

// ---------------- K4: out[t,d] = invS[t]*sum_p parts + sum_s Dcol[t,s]*MKhot[s,d] + sum_s A[t,s]*K[s,d] ----------------
__global__ __launch_bounds__(512) void k4_final(const float* __restrict__ parts,
                                                const float* __restrict__ A,
                                                const float* __restrict__ K,
                                                const float* __restrict__ Dcolg,
                                                const float* __restrict__ MKhot,
                                                const float* __restrict__ invSg,
                                                float* __restrict__ out) {
    __shared__ float Arow[BB];
    __shared__ float Drow[BB];
    int t = blockIdx.x, d = threadIdx.x;
    if (d < BB) { Arow[d] = A[t * BB + d]; Drow[d] = Dcolg[t * BB + d]; }
    __syncthreads();
    float isv = invSg[t];
    float s1 = 0.f;
    #pragma unroll
    for (int p = 0; p < 32; ++p) s1 += parts[(p * 64 + t) * DD + d];
    float s2 = 0.f;
    for (int i = 0; i < BB; ++i) s2 += Drow[i] * MKhot[i * DD + d];
    float s3 = 0.f;
    for (int i = 0; i < BB; ++i) s3 += Arow[i] * K[i * DD + d];
    out[t * DD + d] = isv * s1 + s2 + s3;
}

extern "C" void kernel_launch(void* const* d_in, const int* in_sizes, int n_in,
                              void* d_out, int out_size, void* d_ws, size_t ws_size,
                              hipStream_t stream) {
    const float* K   = (const float*)d_in[0];   // k: [B,1,D]
    // d_in[1] = u: unused (MU never read for the output)
    const float* MK0 = (const float*)d_in[2];   // memory_knowledge: [D,M]
    // d_in[3] = memory_understanding: unused
    const float* bp  = (const float*)d_in[4];   // beta_param
    const float* gp  = (const float*)d_in[5];   // memory_gamma

    float* ws    = (float*)d_ws;
    float* G     = ws;                  // 4096
    float* Pfx   = G + 4096;            // 4096
    float* S0p   = Pfx + 4096;          // 2*64*8192 = 1048576
    float* n2p   = S0p + 1048576;       // 2*8192    = 16384
    float* Ecold = n2p + 16384;         // 64*8192   = 524288
    float* Scold = Ecold + 524288;      // 64
    float* A     = Scold + 64;          // 4096
    float* Dcol  = A + 4096;            // 4096
    float* invS  = Dcol + 4096;         // 64
    float* MKhot = invS + 64;           // 64*512    = 32768
    float* parts = MKhot + 32768;       // 32*64*512 = 1048576
    int*   hcol  = (int*)(parts + 1048576); // 64 ints
    float* out   = (float*)d_out;       // [B,1,D] f32

    k0_gram   <<<1, 1024, 0, stream>>>(K, G, Pfx);
    k1_s0     <<<dim3(128, 2), 256, 0, stream>>>(K, MK0, S0p, n2p);
    k1b_ecold <<<32, 256, 0, stream>>>(S0p, G, Pfx, n2p, bp, Ecold);
    ks_rowsum <<<64, 256, 0, stream>>>(Ecold, Scold);
    k2_scan   <<<1, 1024, 0, stream>>>(Ecold, G, Pfx, Scold, bp, gp, A, Dcol, hcol, invS);
    k3_u1     <<<dim3(8, 32), 256, 0, stream>>>(Ecold, MK0, parts);
    k3b_gather<<<64, 512, 0, stream>>>(MK0, hcol, MKhot);
    k4_final  <<<64, 512, 0, stream>>>(parts, A, K, Dcol, MKhot, invS, out);
}